// Round 2
// baseline (6620.102 us; speedup 1.0000x reference)
//
#include <hip/hip_runtime.h>

// Problem constants: N=512, BS=64, DIM=256, SIZE=8192
#define T_TOTAL 32768   // N*BS queries
#define D       256
#define K       8192
#define QT      128     // queries per block tile
#define CT      128     // codes per block tile
#define DT      32      // d-chunk staged in LDS
#define LPAD    36      // padded LDS row (floats): 32 data + 4 pad, 16B-aligned
#define KSPLIT  4
#define KSLICE  (K / KSPLIT)   // 2048 codes per block

// ---------------- kernel 1: half squared norms of vocab rows ----------------
__global__ void hv2_kernel(const float* __restrict__ vocab, float* __restrict__ hv2) {
    int code = blockIdx.x * 4 + (threadIdx.x >> 6);
    int lane = threadIdx.x & 63;
    const float4* row = (const float4*)(vocab + (size_t)code * D);
    float4 v = row[lane];
    float s = v.x * v.x + v.y * v.y + v.z * v.z + v.w * v.w;
    #pragma unroll
    for (int off = 32; off; off >>= 1) s += __shfl_down(s, off, 64);
    if (lane == 0) hv2[code] = 0.5f * s;
}

// -------- kernel 2: per-K-slice argmin of (0.5*|v|^2 - x.v), 8x8 micro-tile --------
// grid: (T/QT, KSPLIT); block: 256 = 16x16 threads
// partial[s*T + q] = (best_val, best_idx_as_float) for slice s
__launch_bounds__(256, 3)
__global__ void argmin_kernel(const float* __restrict__ seq,
                              const float* __restrict__ vocab,
                              const float* __restrict__ hv2,
                              float2* __restrict__ partial) {
    __shared__ float Qs[QT][LPAD];   // 18.4 KB
    __shared__ float Vs[CT][LPAD];   // 18.4 KB -> 36.9 KB total

    const int t  = threadIdx.x;
    const int tx = t & 15;           // code lane:  c = tx + 16*j
    const int ty = t >> 4;           // query lane: q = ty + 16*i
    const int q0 = blockIdx.x * QT;
    const int k0 = blockIdx.y * KSLICE;

    const float4* seq4 = (const float4*)seq;
    const float4* voc4 = (const float4*)vocab;

    float best[8];
    int   bidx[8];
    #pragma unroll
    for (int i = 0; i < 8; ++i) { best[i] = 3.4e38f; bidx[i] = 0; }

    for (int c0 = k0; c0 < k0 + KSLICE; c0 += CT) {
        float acc[8][8];
        #pragma unroll
        for (int i = 0; i < 8; ++i)
            #pragma unroll
            for (int j = 0; j < 8; ++j) acc[i][j] = 0.0f;

        for (int dt = 0; dt < D; dt += DT) {
            __syncthreads();
            // stage Q chunk: 128 rows x 8 float4 (1024 f4s, 4/thread)
            #pragma unroll
            for (int i = 0; i < 4; ++i) {
                int f  = t + 256 * i;
                int r  = f >> 3;
                int c4 = f & 7;
                *(float4*)&Qs[r][c4 * 4] =
                    seq4[(size_t)(q0 + r) * (D / 4) + (dt / 4) + c4];
            }
            // stage V chunk: 128 rows x 8 float4
            #pragma unroll
            for (int i = 0; i < 4; ++i) {
                int f  = t + 256 * i;
                int r  = f >> 3;
                int c4 = f & 7;
                *(float4*)&Vs[r][c4 * 4] =
                    voc4[(size_t)(c0 + r) * (D / 4) + (dt / 4) + c4];
            }
            __syncthreads();

            // compute: 8 dc-steps; per step 16 ds_read_b128 + 256 v_fma
            #pragma unroll
            for (int dc = 0; dc < DT; dc += 4) {
                float4 qf[8], vf[8];
                #pragma unroll
                for (int i = 0; i < 8; ++i) qf[i] = *(const float4*)&Qs[ty + 16 * i][dc];
                #pragma unroll
                for (int j = 0; j < 8; ++j) vf[j] = *(const float4*)&Vs[tx + 16 * j][dc];
                #pragma unroll
                for (int i = 0; i < 8; ++i)
                    #pragma unroll
                    for (int j = 0; j < 8; ++j) {
                        float a = acc[i][j];
                        a = fmaf(qf[i].x, vf[j].x, a);
                        a = fmaf(qf[i].y, vf[j].y, a);
                        a = fmaf(qf[i].z, vf[j].z, a);
                        a = fmaf(qf[i].w, vf[j].w, a);
                        acc[i][j] = a;
                    }
            }
        }

        // epilogue: s = 0.5*|v|^2 - dot; running first-argmin (c ascending per lane)
        #pragma unroll
        for (int j = 0; j < 8; ++j) {
            int c = c0 + tx + 16 * j;
            float hv = hv2[c];
            #pragma unroll
            for (int i = 0; i < 8; ++i) {
                float s = hv - acc[i][j];
                if (s < best[i]) { best[i] = s; bidx[i] = c; }
            }
        }
    }

    // reduce across the 16 tx-lanes per query (tx == lane&15 since wave=64)
    #pragma unroll
    for (int off = 1; off < 16; off <<= 1) {
        #pragma unroll
        for (int i = 0; i < 8; ++i) {
            float ob = __shfl_xor(best[i], off, 64);
            int   oi = __shfl_xor(bidx[i], off, 64);
            if (ob < best[i] || (ob == best[i] && oi < bidx[i])) {
                best[i] = ob; bidx[i] = oi;
            }
        }
    }
    if (tx == 0) {
        #pragma unroll
        for (int i = 0; i < 8; ++i) {
            int q = q0 + ty + 16 * i;
            partial[(size_t)blockIdx.y * T_TOTAL + q] = make_float2(best[i], (float)bidx[i]);
        }
    }
}

// ---------------- kernel 3: fold K-slices (first-argmin tie rule) ----------------
__global__ void reduce_kernel(const float2* __restrict__ partial, int* __restrict__ idx) {
    int q = blockIdx.x * 256 + threadIdx.x;
    float bm = 3.4e38f;
    int   bi = 0;
    #pragma unroll
    for (int s = 0; s < KSPLIT; ++s) {
        float2 p = partial[(size_t)s * T_TOTAL + q];
        if (p.x < bm) { bm = p.x; bi = (int)p.y; }   // strict <: lower slice wins ties
    }
    idx[q] = bi;
}

// ---------------- kernel 4: gather vocab rows + emit indices as f32 ----------------
__global__ void gather_kernel(const float* __restrict__ vocab,
                              const int* __restrict__ idx,
                              float* __restrict__ out) {
    int r    = blockIdx.x * 4 + (threadIdx.x >> 6);  // one wave per output row
    int lane = threadIdx.x & 63;
    int k = idx[r];
    const float4* src = (const float4*)(vocab + (size_t)k * D);
    float4*       dst = (float4*)(out + (size_t)r * D);
    dst[lane] = src[lane];
    if (lane == 0) out[(size_t)T_TOTAL * D + r] = (float)k;
}

extern "C" void kernel_launch(void* const* d_in, const int* in_sizes, int n_in,
                              void* d_out, int out_size, void* d_ws, size_t ws_size,
                              hipStream_t stream) {
    const float* seq   = (const float*)d_in[0];   // [T, D] f32
    const float* vocab = (const float*)d_in[1];   // [K, D] f32
    float* out = (float*)d_out;

    float* hv2 = (float*)d_ws;                               // K floats
    int*   idx = (int*)((char*)d_ws + K * sizeof(float));    // T ints

    // Partial (min,idx) pairs live at the head of d_out's quantized region
    // (KSPLIT*T*8 = 1 MB << 32 MB) and are fully overwritten by gather afterwards.
    float2* partial = (float2*)d_out;

    hipLaunchKernelGGL(hv2_kernel,    dim3(K / 4),               dim3(256), 0, stream, vocab, hv2);
    hipLaunchKernelGGL(argmin_kernel, dim3(T_TOTAL / QT, KSPLIT), dim3(256), 0, stream,
                       seq, vocab, hv2, partial);
    hipLaunchKernelGGL(reduce_kernel, dim3(T_TOTAL / 256),       dim3(256), 0, stream, partial, idx);
    hipLaunchKernelGGL(gather_kernel, dim3(T_TOTAL / 4),         dim3(256), 0, stream, vocab, idx, out);
}

// Round 3
// 2043.764 us; speedup vs baseline: 3.2392x; 3.2392x over previous
//
#include <hip/hip_runtime.h>

// Problem constants: N=512, BS=64, DIM=256, SIZE=8192
#define T_TOTAL 32768   // N*BS queries
#define D       256
#define K       8192
#define NQ      8       // queries per wave (wave-uniform, via scalar/broadcast loads)
#define QT      32      // queries per block = 4 waves * NQ
#define CT      512     // codes per block tile (8 per lane)
#define DT      8       // d-chunk staged in LDS
#define VROW    12      // LDS row floats: 8 data + 4 pad (48 B -> quad = 3*lane mod 8, conflict-free)

// ---------------- kernel 1: half squared norms of vocab rows ----------------
__global__ void hv2_kernel(const float* __restrict__ vocab, float* __restrict__ hv2) {
    int code = blockIdx.x * 4 + (threadIdx.x >> 6);
    int lane = threadIdx.x & 63;
    const float4* row = (const float4*)(vocab + (size_t)code * D);
    float4 v = row[lane];
    float s = v.x * v.x + v.y * v.y + v.z * v.z + v.w * v.w;
    #pragma unroll
    for (int off = 32; off; off >>= 1) s += __shfl_down(s, off, 64);
    if (lane == 0) hv2[code] = 0.5f * s;
}

// -------- kernel 2: argmin of (0.5*|v|^2 - x.v) --------
// block = 256 thr = 4 waves; wave owns NQ=8 queries (uniform), lane owns 8 codes of CT=512.
// Q operand: wave-uniform global loads (SMEM/broadcast path, off the LDS pipe).
// V operand: LDS-staged, 16 ds_read_b128 per 512 FMAs per lane.
__launch_bounds__(256, 2)
__global__ void argmin_kernel(const float* __restrict__ seq,
                              const float* __restrict__ vocab,
                              const float* __restrict__ hv2,
                              int* __restrict__ out_idx) {
    __shared__ float Vs[CT * VROW];   // 24 KB

    const int t    = threadIdx.x;
    const int lane = t & 63;
    const int wave = __builtin_amdgcn_readfirstlane(t >> 6);  // force wave-uniform
    const int q0   = blockIdx.x * QT + wave * NQ;             // uniform per wave

    float best[NQ];
    int   bidx[NQ];
    #pragma unroll
    for (int i = 0; i < NQ; ++i) { best[i] = 3.4e38f; bidx[i] = 0; }

    for (int c0 = 0; c0 < K; c0 += CT) {
        float acc[NQ][8];
        #pragma unroll
        for (int i = 0; i < NQ; ++i)
            #pragma unroll
            for (int j = 0; j < 8; ++j) acc[i][j] = 0.0f;

        for (int dt = 0; dt < D; dt += DT) {
            __syncthreads();   // previous chunk's reads done before overwrite
            // stage V chunk: 512 rows x 8 floats; thread -> 4 float4 (rows t/2, halves t&1)
            #pragma unroll
            for (int i = 0; i < 4; ++i) {
                int f = t + 256 * i;          // 0..1023
                int r = f >> 1;
                int h = f & 1;
                float4 v = *(const float4*)(vocab + (size_t)(c0 + r) * D + dt + h * 4);
                *(float4*)(&Vs[r * VROW + h * 4]) = v;
            }
            __syncthreads();

            // compute: two 4-d halves; per half: 8 ds_read_b128 (V) + 8 uniform Q loads + 256 FMA
            #pragma unroll
            for (int h = 0; h < 2; ++h) {
                float4 vf[8];
                #pragma unroll
                for (int j = 0; j < 8; ++j)
                    vf[j] = *(const float4*)(&Vs[(lane + 64 * j) * VROW + h * 4]);
                #pragma unroll
                for (int i = 0; i < NQ; ++i) {
                    // wave-uniform address -> scalar (s_load_dwordx4) or broadcast VMEM
                    float4 qv = *(const float4*)(seq + (size_t)(q0 + i) * D + dt + h * 4);
                    #pragma unroll
                    for (int j = 0; j < 8; ++j) {
                        float a = acc[i][j];
                        a = fmaf(qv.x, vf[j].x, a);
                        a = fmaf(qv.y, vf[j].y, a);
                        a = fmaf(qv.z, vf[j].z, a);
                        a = fmaf(qv.w, vf[j].w, a);
                        acc[i][j] = a;
                    }
                }
            }
        }

        // epilogue: s = 0.5*|v|^2 - dot ; per-lane ascending-c running first-argmin
        #pragma unroll
        for (int j = 0; j < 8; ++j) {
            int c = c0 + lane + 64 * j;
            float hv = hv2[c];
            #pragma unroll
            for (int i = 0; i < NQ; ++i) {
                float s = hv - acc[i][j];
                if (s < best[i]) { best[i] = s; bidx[i] = c; }
            }
        }
    }

    // full-wave butterfly argmin per query (tie -> smaller code index)
    #pragma unroll
    for (int off = 1; off < 64; off <<= 1) {
        #pragma unroll
        for (int i = 0; i < NQ; ++i) {
            float ob = __shfl_xor(best[i], off, 64);
            int   oi = __shfl_xor(bidx[i], off, 64);
            if (ob < best[i] || (ob == best[i] && oi < bidx[i])) {
                best[i] = ob; bidx[i] = oi;
            }
        }
    }
    if (lane == 0) {
        #pragma unroll
        for (int i = 0; i < NQ; ++i) out_idx[q0 + i] = bidx[i];
    }
}

// ---------------- kernel 3: gather vocab rows + emit indices as f32 ----------------
__global__ void gather_kernel(const float* __restrict__ vocab,
                              const int* __restrict__ idx,
                              float* __restrict__ out) {
    int r    = blockIdx.x * 4 + (threadIdx.x >> 6);  // one wave per output row
    int lane = threadIdx.x & 63;
    int k = idx[r];
    const float4* src = (const float4*)(vocab + (size_t)k * D);
    float4*       dst = (float4*)(out + (size_t)r * D);
    dst[lane] = src[lane];
    if (lane == 0) out[(size_t)T_TOTAL * D + r] = (float)k;
}

extern "C" void kernel_launch(void* const* d_in, const int* in_sizes, int n_in,
                              void* d_out, int out_size, void* d_ws, size_t ws_size,
                              hipStream_t stream) {
    const float* seq   = (const float*)d_in[0];   // [T, D] f32
    const float* vocab = (const float*)d_in[1];   // [K, D] f32
    float* out = (float*)d_out;

    float* hv2 = (float*)d_ws;                               // K floats
    int*   idx = (int*)((char*)d_ws + K * sizeof(float));    // T ints

    hipLaunchKernelGGL(hv2_kernel,    dim3(K / 4),        dim3(256), 0, stream, vocab, hv2);
    hipLaunchKernelGGL(argmin_kernel, dim3(T_TOTAL / QT), dim3(256), 0, stream, seq, vocab, hv2, idx);
    hipLaunchKernelGGL(gather_kernel, dim3(T_TOTAL / 4),  dim3(256), 0, stream, vocab, idx, out);
}

// Round 6
// 607.112 us; speedup vs baseline: 10.9043x; 3.3664x over previous
//
#include <hip/hip_runtime.h>

// Problem constants: N=512, BS=64, DIM=256, SIZE=8192
#define T_TOTAL 32768   // N*BS queries
#define D       256
#define K       8192
#define BQ      128     // queries per block tile
#define BC      128     // codes per block tile
#define DC      32      // fp32 dims staged per LDS chunk
#define KSPLIT  4
#define KSLICE  (K / KSPLIT)
#define NSLICE  (KSPLIT * 2)   // 2 wn-halves per K-slice write disjoint partials

typedef _Float16 half4f __attribute__((ext_vector_type(4)));
typedef _Float16 half8f __attribute__((ext_vector_type(8)));
typedef float    floatx4 __attribute__((ext_vector_type(4)));

// ---------------- kernel 1: half squared norms of vocab rows (fp32 exact) ----------------
__global__ void hv2_kernel(const float* __restrict__ vocab, float* __restrict__ hv2) {
    int code = blockIdx.x * 4 + (threadIdx.x >> 6);
    int lane = threadIdx.x & 63;
    const float4* row = (const float4*)(vocab + (size_t)code * D);
    float4 v = row[lane];
    float s = v.x * v.x + v.y * v.y + v.z * v.z + v.w * v.w;
    #pragma unroll
    for (int off = 32; off; off >>= 1) s += __shfl_down(s, off, 64);
    if (lane == 0) hv2[code] = 0.5f * s;
}

// Split fp32 x into fp16 hi (RNE) and fp16 lo = fp16(x - hi). x ~= hi + lo, residual ~2^-22*|x|.
__device__ __forceinline__ _Float16 hi16(float x) { return (_Float16)x; }
__device__ __forceinline__ _Float16 lo16(float x, _Float16 h) { return (_Float16)(x - (float)h); }

__device__ __forceinline__ void split4(float4 v, half4f& h, half4f& l) {
    _Float16 hx = hi16(v.x), hy = hi16(v.y), hz = hi16(v.z), hw = hi16(v.w);
    h = (half4f){hx, hy, hz, hw};
    l = (half4f){lo16(v.x, hx), lo16(v.y, hy), lo16(v.z, hz), lo16(v.w, hw)};
}

// -------- kernel 2: MFMA argmin of (0.5*|v|^2 - x.v) via 4-term fp16-split GEMM --------
// block 256 thr = 4 waves; block tile 128q x 128c; wave tile 64x64 (4x4 of 16x16x32 f16).
// grid: (T/BQ, KSPLIT). Each wave covers HALF the codes (wn) of its K-slice, so it writes
// its own partial slice (blockIdx.y*2 + wn) -> 8 disjoint slices, NO cross-wave race.
__launch_bounds__(256, 2)
__global__ void argmin_kernel(const float* __restrict__ seq,
                              const float* __restrict__ vocab,
                              const float* __restrict__ hv2,
                              float2* __restrict__ partial) {
    __shared__ _Float16 Ah[BQ * DC];   // 8 KB
    __shared__ _Float16 Al[BQ * DC];   // 8 KB
    __shared__ _Float16 Bh[BC * DC];   // 8 KB
    __shared__ _Float16 Bl[BC * DC];   // 8 KB  -> 32 KB total

    const int t    = threadIdx.x;
    const int lane = t & 63;
    const int w    = t >> 6;
    const int wm   = w >> 1;          // wave row-half (0..1)
    const int wn   = w & 1;           // wave col-half (0..1)
    const int q0   = blockIdx.x * BQ;
    const int k0   = blockIdx.y * KSLICE;

    const float4* seq4 = (const float4*)seq;
    const float4* voc4 = (const float4*)vocab;

    // frag read offset within a 16-row x 32-k part tile (in halves):
    // lane reads A[m=lane&15][k=(lane>>4)*8 + j]  -> contiguous 1024B per tile (conflict-free)
    const int fofs = (lane & 15) * DC + (lane >> 4) * 8;

    float best[16];
    int   bidx[16];
    #pragma unroll
    for (int b = 0; b < 16; ++b) { best[b] = 3.4e38f; bidx[b] = 0; }

    for (int c0 = k0; c0 < k0 + KSLICE; c0 += BC) {
        floatx4 acc[4][4];
        #pragma unroll
        for (int mi = 0; mi < 4; ++mi)
            #pragma unroll
            for (int nj = 0; nj < 4; ++nj) acc[mi][nj] = (floatx4){0.f, 0.f, 0.f, 0.f};

        for (int dt = 0; dt < D; dt += DC) {
            __syncthreads();
            // stage A (seq): 128 rows x 8 float4 = 1024 f4, 4 per thread
            #pragma unroll
            for (int i = 0; i < 4; ++i) {
                int f   = t + 256 * i;
                int row = f >> 3;
                int d4  = f & 7;
                float4 v = seq4[(size_t)(q0 + row) * (D / 4) + (dt >> 2) + d4];
                half4f h, l;
                split4(v, h, l);
                *(half4f*)&Ah[row * DC + d4 * 4] = h;
                *(half4f*)&Al[row * DC + d4 * 4] = l;
            }
            // stage B (vocab): 128 rows x 8 float4
            #pragma unroll
            for (int i = 0; i < 4; ++i) {
                int f   = t + 256 * i;
                int row = f >> 3;
                int d4  = f & 7;
                float4 v = voc4[(size_t)(c0 + row) * (D / 4) + (dt >> 2) + d4];
                half4f h, l;
                split4(v, h, l);
                *(half4f*)&Bh[row * DC + d4 * 4] = h;
                *(half4f*)&Bl[row * DC + d4 * 4] = l;
            }
            __syncthreads();

            // load fragments: A row-blocks wm*4+mi, B col-blocks wn*4+nj
            half8f ah[4], al[4], bh[4], bl[4];
            #pragma unroll
            for (int mi = 0; mi < 4; ++mi) {
                int rb = (wm * 4 + mi) * 16 * DC;
                ah[mi] = *(const half8f*)&Ah[rb + fofs];
                al[mi] = *(const half8f*)&Al[rb + fofs];
            }
            #pragma unroll
            for (int nj = 0; nj < 4; ++nj) {
                int cb = (wn * 4 + nj) * 16 * DC;
                bh[nj] = *(const half8f*)&Bh[cb + fofs];
                bl[nj] = *(const half8f*)&Bl[cb + fofs];
            }

            // 4-term MFMAs, small terms first (ll, lh, hl), dominant hh last
            #pragma unroll
            for (int mi = 0; mi < 4; ++mi)
                #pragma unroll
                for (int nj = 0; nj < 4; ++nj) {
                    floatx4 a = acc[mi][nj];
                    a = __builtin_amdgcn_mfma_f32_16x16x32_f16(al[mi], bl[nj], a, 0, 0, 0);
                    a = __builtin_amdgcn_mfma_f32_16x16x32_f16(al[mi], bh[nj], a, 0, 0, 0);
                    a = __builtin_amdgcn_mfma_f32_16x16x32_f16(ah[mi], bl[nj], a, 0, 0, 0);
                    a = __builtin_amdgcn_mfma_f32_16x16x32_f16(ah[mi], bh[nj], a, 0, 0, 0);
                    acc[mi][nj] = a;
                }
        }

        // epilogue: s = 0.5*|v|^2 - dot; running first-argmin.
        // C/D layout (verified): col = lane&15, row = (lane>>4)*4 + reg
        #pragma unroll
        for (int nj = 0; nj < 4; ++nj) {
            int c = c0 + (wn * 4 + nj) * 16 + (lane & 15);
            float hv = hv2[c];
            #pragma unroll
            for (int mi = 0; mi < 4; ++mi)
                #pragma unroll
                for (int r = 0; r < 4; ++r) {
                    float s = hv - acc[mi][nj][r];
                    int b = mi * 4 + r;
                    if (s < best[b]) { best[b] = s; bidx[b] = c; }
                }
        }
    }

    // reduce across the 16 lanes (same lane>>4 group = same rows, 16 different cols)
    #pragma unroll
    for (int off = 1; off < 16; off <<= 1) {
        #pragma unroll
        for (int b = 0; b < 16; ++b) {
            float ob = __shfl_xor(best[b], off, 64);
            int   oi = __shfl_xor(bidx[b], off, 64);
            if (ob < best[b] || (ob == best[b] && oi < bidx[b])) {
                best[b] = ob; bidx[b] = oi;
            }
        }
    }
    if ((lane & 15) == 0) {
        const size_t sl = (size_t)(blockIdx.y * 2 + wn) * T_TOTAL;  // disjoint per wn!
        #pragma unroll
        for (int mi = 0; mi < 4; ++mi)
            #pragma unroll
            for (int r = 0; r < 4; ++r) {
                int q = q0 + wm * 64 + mi * 16 + (lane >> 4) * 4 + r;
                int b = mi * 4 + r;
                partial[sl + q] = make_float2(best[b], (float)bidx[b]);
            }
    }
}

// ------- kernel 3: fold 8 partial slices (value min, tie -> smaller global index) -------
__global__ void reduce_kernel(const float2* __restrict__ partial, int* __restrict__ idx) {
    int q = blockIdx.x * 256 + threadIdx.x;
    float bm = 3.4e38f;
    int   bi = 0x7fffffff;
    #pragma unroll
    for (int s = 0; s < NSLICE; ++s) {
        float2 p = partial[(size_t)s * T_TOTAL + q];
        int pi = (int)p.y;
        if (p.x < bm || (p.x == bm && pi < bi)) { bm = p.x; bi = pi; }
    }
    idx[q] = bi;
}

// ---------------- kernel 4: gather vocab rows + emit indices as f32 ----------------
__global__ void gather_kernel(const float* __restrict__ vocab,
                              const int* __restrict__ idx,
                              float* __restrict__ out) {
    int r    = blockIdx.x * 4 + (threadIdx.x >> 6);  // one wave per output row
    int lane = threadIdx.x & 63;
    int k = idx[r];
    const float4* src = (const float4*)(vocab + (size_t)k * D);
    float4*       dst = (float4*)(out + (size_t)r * D);
    dst[lane] = src[lane];
    if (lane == 0) out[(size_t)T_TOTAL * D + r] = (float)k;
}

extern "C" void kernel_launch(void* const* d_in, const int* in_sizes, int n_in,
                              void* d_out, int out_size, void* d_ws, size_t ws_size,
                              hipStream_t stream) {
    const float* seq   = (const float*)d_in[0];   // [T, D] f32
    const float* vocab = (const float*)d_in[1];   // [K, D] f32
    float* out = (float*)d_out;

    float* hv2 = (float*)d_ws;                               // K floats
    int*   idx = (int*)((char*)d_ws + K * sizeof(float));    // T ints

    // Partials live at the head of d_out's quantized region (NSLICE*T*8 = 2 MB << 33.6 MB),
    // consumed by reduce_kernel, then fully overwritten by gather_kernel.
    float2* partial = (float2*)d_out;

    hipLaunchKernelGGL(hv2_kernel,    dim3(K / 4),                dim3(256), 0, stream, vocab, hv2);
    hipLaunchKernelGGL(argmin_kernel, dim3(T_TOTAL / BQ, KSPLIT), dim3(256), 0, stream,
                       seq, vocab, hv2, partial);
    hipLaunchKernelGGL(reduce_kernel, dim3(T_TOTAL / 256),        dim3(256), 0, stream, partial, idx);
    hipLaunchKernelGGL(gather_kernel, dim3(T_TOTAL / 4),          dim3(256), 0, stream, vocab, idx, out);
}

// Round 7
// 527.609 us; speedup vs baseline: 12.5474x; 1.1507x over previous
//
#include <hip/hip_runtime.h>

// Problem constants: N=512, BS=64, DIM=256, SIZE=8192
#define T_TOTAL 32768   // N*BS queries
#define D       256
#define K       8192
#define BQ      64      // queries per block tile (4 row-tiles of 16)
#define BC      128     // codes per c0 tile (8 code-tiles of 16)
#define KSPLIT  4
#define KSLICE  (K / KSPLIT)
#define NSLICE  (KSPLIT * 2)        // wn-halves write disjoint partial slices
#define NCT     (K / 16)            // 512 code-tiles
#define KT_STRIDE (NCT * 64 * 8)    // halves per kt plane = 262144

typedef _Float16 half4f  __attribute__((ext_vector_type(4)));
typedef _Float16 half8f  __attribute__((ext_vector_type(8)));
typedef float    floatx4 __attribute__((ext_vector_type(4)));

// d_out scratch layout (floats): [0,524288) partial (8 slices x T x float2),
// then Bhi (1048576 f), then Blo (1048576 f). All consumed before gather overwrites.
#define PARTIAL_F 524288
#define BSPLIT_F  (PARTIAL_F)
#define BHALVES   2097152   // halves per B array (8*512*64*8)

// ---------------- kernel 1: half squared norms of vocab rows (fp32 exact) ----------------
__global__ void hv2_kernel(const float* __restrict__ vocab, float* __restrict__ hv2) {
    int code = blockIdx.x * 4 + (threadIdx.x >> 6);
    int lane = threadIdx.x & 63;
    const float4* row = (const float4*)(vocab + (size_t)code * D);
    float4 v = row[lane];
    float s = v.x * v.x + v.y * v.y + v.z * v.z + v.w * v.w;
    #pragma unroll
    for (int off = 32; off; off >>= 1) s += __shfl_down(s, off, 64);
    if (lane == 0) hv2[code] = 0.5f * s;
}

__device__ __forceinline__ _Float16 hi16(float x) { return (_Float16)x; }
__device__ __forceinline__ _Float16 lo16(float x, _Float16 h) { return (_Float16)(x - (float)h); }
__device__ __forceinline__ void split4(float4 v, half4f& h, half4f& l) {
    _Float16 hx = hi16(v.x), hy = hi16(v.y), hz = hi16(v.z), hw = hi16(v.w);
    h = (half4f){hx, hy, hz, hw};
    l = (half4f){lo16(v.x, hx), lo16(v.y, hy), lo16(v.z, hz), lo16(v.w, hw)};
}

// ------- kernel 1b: split vocab into fp16 hi/lo, fragment-order global layout -------
// layout: tile(kt 0..7, ct 0..511): 64 lanes x 8 halves; element (code c, dim k) ->
// kt=k>>5, ct=c>>4, lane=(c&15)+16*((k&31)>>3), j=k&7. Address=((kt*512+ct)*64+lane)*8+j.
__global__ void bsplit_kernel(const float* __restrict__ vocab,
                              _Float16* __restrict__ bhi, _Float16* __restrict__ blo) {
    const int ct = blockIdx.x;           // 512 blocks, one 16-code tile each
    const int t  = threadIdx.x;
    const int k4 = t & 63;               // float4 index along D
    const float4* voc4 = (const float4*)vocab;
    const int kt = k4 >> 3, kg = (k4 >> 1) & 3, h = k4 & 1;
    #pragma unroll
    for (int ci = 0; ci < 4; ++ci) {
        int cc = (t >> 6) * 4 + ci;      // code within tile
        float4 v = voc4[(size_t)(ct * 16 + cc) * (D / 4) + k4];
        half4f hh, ll;
        split4(v, hh, ll);
        size_t off = (((size_t)kt * NCT + ct) * 64 + (cc + 16 * kg)) * 8 + h * 4;
        *(half4f*)&bhi[off] = hh;
        *(half4f*)&blo[off] = ll;
    }
}

// -------- kernel 2: MFMA argmin, barrier-free K-loop --------
// block 256 = 4 waves (wm,wn in 2x2); wave tile 32q x 64c; grid (T/BQ, KSPLIT).
// A (seq) split once into fragment-order LDS; B fragments read directly from global.
__launch_bounds__(256, 2)
__global__ void argmin_kernel(const float* __restrict__ seq,
                              const _Float16* __restrict__ bhi,
                              const _Float16* __restrict__ blo,
                              const float* __restrict__ hv2,
                              float2* __restrict__ partial) {
    __shared__ _Float16 AhL[4 * 8 * 64 * 8];   // 32 KB: [rt][kt][lane][8]
    __shared__ _Float16 AlL[4 * 8 * 64 * 8];   // 32 KB

    const int t    = threadIdx.x;
    const int lane = t & 63;
    const int w    = t >> 6;
    const int wm   = w >> 1;            // query half (rt pair)
    const int wn   = w & 1;             // code half (nj quad)
    const int q0   = blockIdx.x * BQ;
    const int k0   = blockIdx.y * KSLICE;

    const float4* seq4 = (const float4*)seq;

    // ---- prologue: split A (64 rows x 256 dims) into fragment-order LDS, once ----
    #pragma unroll
    for (int i = 0; i < 16; ++i) {
        int f   = t + 256 * i;          // 0..4095 float4s
        int row = f >> 6;               // 0..63
        int d4  = f & 63;               // float4 along D
        float4 v = seq4[(size_t)(q0 + row) * (D / 4) + d4];
        half4f h, l;
        split4(v, h, l);
        int kt = d4 >> 3, kg = (d4 >> 1) & 3, hh = d4 & 1;
        int off = ((((row >> 4) * 8 + kt) * 64) + ((row & 15) + 16 * kg)) * 8 + hh * 4;
        *(half4f*)&AhL[off] = h;
        *(half4f*)&AlL[off] = l;
    }
    __syncthreads();   // the ONLY barrier

    float best[8];
    int   bidx[8];
    #pragma unroll
    for (int b = 0; b < 8; ++b) { best[b] = 3.4e38f; bidx[b] = 0; }

    // per-lane invariant bases
    const _Float16* bh_l = bhi + (size_t)lane * 8;
    const _Float16* bl_l = blo + (size_t)lane * 8;

    for (int c0i = 0; c0i < KSLICE / BC; ++c0i) {   // 16 c0 tiles
        const int c0  = k0 + c0i * BC;
        const int ct0 = (c0 >> 4) + wn * 4;

        floatx4 acc[2][4];
        #pragma unroll
        for (int mi = 0; mi < 2; ++mi)
            #pragma unroll
            for (int nj = 0; nj < 4; ++nj) acc[mi][nj] = (floatx4){0.f, 0.f, 0.f, 0.f};

        #pragma unroll 4
        for (int kt = 0; kt < 8; ++kt) {
            // A fragments from LDS (lane*16B contiguous: conflict-free b128)
            const int a0 = (((wm * 2 + 0) * 8 + kt) * 64 + lane) * 8;
            const int a1 = (((wm * 2 + 1) * 8 + kt) * 64 + lane) * 8;
            half8f ah0 = *(const half8f*)&AhL[a0];
            half8f al0 = *(const half8f*)&AlL[a0];
            half8f ah1 = *(const half8f*)&AhL[a1];
            half8f al1 = *(const half8f*)&AlL[a1];
            // B fragments direct from global (coalesced b128, L2-resident)
            const size_t kb = (size_t)kt * KT_STRIDE + (size_t)ct0 * 512;
            #pragma unroll
            for (int nj = 0; nj < 4; ++nj) {
                half8f bh = *(const half8f*)&bh_l[kb + nj * 512];
                half8f bl = *(const half8f*)&bl_l[kb + nj * 512];
                floatx4 a = acc[0][nj];
                a = __builtin_amdgcn_mfma_f32_16x16x32_f16(al0, bl, a, 0, 0, 0);
                a = __builtin_amdgcn_mfma_f32_16x16x32_f16(al0, bh, a, 0, 0, 0);
                a = __builtin_amdgcn_mfma_f32_16x16x32_f16(ah0, bl, a, 0, 0, 0);
                a = __builtin_amdgcn_mfma_f32_16x16x32_f16(ah0, bh, a, 0, 0, 0);
                acc[0][nj] = a;
                floatx4 b = acc[1][nj];
                b = __builtin_amdgcn_mfma_f32_16x16x32_f16(al1, bl, b, 0, 0, 0);
                b = __builtin_amdgcn_mfma_f32_16x16x32_f16(al1, bh, b, 0, 0, 0);
                b = __builtin_amdgcn_mfma_f32_16x16x32_f16(ah1, bl, b, 0, 0, 0);
                b = __builtin_amdgcn_mfma_f32_16x16x32_f16(ah1, bh, b, 0, 0, 0);
                acc[1][nj] = b;
            }
        }

        // epilogue: s = 0.5*|v|^2 - dot; running first-argmin (ascending c per lane).
        // C/D layout: col = lane&15, row = (lane>>4)*4 + reg
        #pragma unroll
        for (int nj = 0; nj < 4; ++nj) {
            int c = c0 + (wn * 4 + nj) * 16 + (lane & 15);
            float hv = hv2[c];
            #pragma unroll
            for (int mi = 0; mi < 2; ++mi)
                #pragma unroll
                for (int r = 0; r < 4; ++r) {
                    float s = hv - acc[mi][nj][r];
                    int b = mi * 4 + r;
                    if (s < best[b]) { best[b] = s; bidx[b] = c; }
                }
        }
    }

    // reduce across the 16 col-lanes (same rows, 16 different cols)
    #pragma unroll
    for (int off = 1; off < 16; off <<= 1) {
        #pragma unroll
        for (int b = 0; b < 8; ++b) {
            float ob = __shfl_xor(best[b], off, 64);
            int   oi = __shfl_xor(bidx[b], off, 64);
            if (ob < best[b] || (ob == best[b] && oi < bidx[b])) {
                best[b] = ob; bidx[b] = oi;
            }
        }
    }
    if ((lane & 15) == 0) {
        const size_t sl = (size_t)(blockIdx.y * 2 + wn) * T_TOTAL;  // disjoint per wn
        #pragma unroll
        for (int mi = 0; mi < 2; ++mi)
            #pragma unroll
            for (int r = 0; r < 4; ++r) {
                int q = q0 + (wm * 2 + mi) * 16 + (lane >> 4) * 4 + r;
                partial[sl + q] = make_float2(best[mi * 4 + r], (float)bidx[mi * 4 + r]);
            }
    }
}

// ------- kernel 3: fold 8 partial slices (value min, tie -> smaller global index) -------
__global__ void reduce_kernel(const float2* __restrict__ partial, int* __restrict__ idx) {
    int q = blockIdx.x * 256 + threadIdx.x;
    float bm = 3.4e38f;
    int   bi = 0x7fffffff;
    #pragma unroll
    for (int s = 0; s < NSLICE; ++s) {
        float2 p = partial[(size_t)s * T_TOTAL + q];
        int pi = (int)p.y;
        if (p.x < bm || (p.x == bm && pi < bi)) { bm = p.x; bi = pi; }
    }
    idx[q] = bi;
}

// ---------------- kernel 4: gather vocab rows + emit indices as f32 ----------------
__global__ void gather_kernel(const float* __restrict__ vocab,
                              const int* __restrict__ idx,
                              float* __restrict__ out) {
    int r    = blockIdx.x * 4 + (threadIdx.x >> 6);  // one wave per output row
    int lane = threadIdx.x & 63;
    int k = idx[r];
    const float4* src = (const float4*)(vocab + (size_t)k * D);
    float4*       dst = (float4*)(out + (size_t)r * D);
    dst[lane] = src[lane];
    if (lane == 0) out[(size_t)T_TOTAL * D + r] = (float)k;
}

extern "C" void kernel_launch(void* const* d_in, const int* in_sizes, int n_in,
                              void* d_out, int out_size, void* d_ws, size_t ws_size,
                              hipStream_t stream) {
    const float* seq   = (const float*)d_in[0];   // [T, D] f32
    const float* vocab = (const float*)d_in[1];   // [K, D] f32
    float* out = (float*)d_out;

    float* hv2 = (float*)d_ws;                               // K floats
    int*   idx = (int*)((char*)d_ws + K * sizeof(float));    // T ints

    float2*   partial = (float2*)d_out;                      // 2 MB at head
    _Float16* bhi = (_Float16*)(out + BSPLIT_F);             // 4 MB
    _Float16* blo = bhi + BHALVES;                           // 4 MB
    // all scratch within d_out's quantized region; consumed before gather overwrites

    hipLaunchKernelGGL(hv2_kernel,    dim3(K / 4),                dim3(256), 0, stream, vocab, hv2);
    hipLaunchKernelGGL(bsplit_kernel, dim3(NCT),                  dim3(256), 0, stream, vocab, bhi, blo);
    hipLaunchKernelGGL(argmin_kernel, dim3(T_TOTAL / BQ, KSPLIT), dim3(256), 0, stream,
                       seq, bhi, blo, hv2, partial);
    hipLaunchKernelGGL(reduce_kernel, dim3(T_TOTAL / 256),        dim3(256), 0, stream, partial, idx);
    hipLaunchKernelGGL(gather_kernel, dim3(T_TOTAL / 4),          dim3(256), 0, stream, vocab, idx, out);
}